// Round 4
// baseline (2032.976 us; speedup 1.0000x reference)
//
#include <hip/hip_runtime.h>
#include <cstddef>
#include <cstdint>

// LSTM_27934467293427 — R8: break MFMA accumulator chains + packed bf16 cvt.
// R7 post-mortem: k2 per-step ~1660cy; 6-deep dependent MFMA accumulate chains
// with ~1 wave/SIMD (no TLP to hide MFMA latency) dominate. Fix: 3 accs/gate
// (depth 2) + tree add of [0] elems. Head wave same. k1 was cvt-bound (~48
// VALU per cvt8): use v_cvt_pk_bf16_f32 (gfx950) -> ~24 ops per 8 elems.

namespace {

constexpr int B_ = 256, S_ = 2048, E_ = 128, H_ = 64, G_ = 256, H2_ = 2;

typedef short short8 __attribute__((ext_vector_type(8)));
typedef float f4 __attribute__((ext_vector_type(4)));

__device__ __forceinline__ float sigm(float x) {
    return __builtin_amdgcn_rcpf(1.0f + __expf(-x));
}
__device__ __forceinline__ float tanh_fast(float x) {
    return 1.0f - 2.0f * __builtin_amdgcn_rcpf(1.0f + __expf(2.0f * x));
}
__device__ __forceinline__ short f2bf(float f) {  // RNE float->bf16
    union { float f; uint32_t u; } a; a.f = f;
    uint32_t r = a.u + 0x7FFFu + ((a.u >> 16) & 1u);
    return (short)(r >> 16);
}
__device__ __forceinline__ float bf2f(short s) {
    union { uint32_t u; float f; } a; a.u = ((uint32_t)(uint16_t)s) << 16;
    return a.f;
}
// packed RNE f32x2 -> bf16x2 (src0 -> low16, src1 -> high16)
__device__ __forceinline__ uint32_t cvtpk(float a, float b) {
    uint32_t r;
    asm("v_cvt_pk_bf16_f32 %0, %1, %2" : "=v"(r) : "v"(a), "v"(b));
    return r;
}
__device__ __forceinline__ void cvt8(float4 a, float4 b, short8& hi, short8& lo) {
    float v[8] = {a.x, a.y, a.z, a.w, b.x, b.y, b.z, b.w};
    uint32_t* hp = (uint32_t*)&hi;
    uint32_t* lp = (uint32_t*)&lo;
    #pragma unroll
    for (int i = 0; i < 4; ++i) {
        const uint32_t h = cvtpk(v[2 * i], v[2 * i + 1]);
        union { uint32_t u; float f; } f0, f1;
        f0.u = h << 16;            // bf2f of low element
        f1.u = h & 0xffff0000u;    // bf2f of high element
        lp[i] = cvtpk(v[2 * i] - f0.f, v[2 * i + 1] - f1.f);
        hp[i] = h;
    }
}

// LDS-only barrier: does NOT drain vmcnt, so global prefetch stays in flight.
__device__ __forceinline__ void sync_lds_only() {
    asm volatile("s_waitcnt lgkmcnt(0)" ::: "memory");
    __builtin_amdgcn_s_barrier();
    asm volatile("" ::: "memory");
}

// ---------------- K1: gx[b][tau][j] = sum_e x[b,cs+tau,e]*Wih[j,e] + bias[j] ----
__global__ __launch_bounds__(256) void k1_gemm(
    const float* __restrict__ x, const int* __restrict__ lengths,
    const float* __restrict__ Wih, const float* __restrict__ bih,
    const float* __restrict__ bhh, float* __restrict__ gx, int cs, int tcLog)
{
    const int Tc = 1 << tcLog;
    const int t = threadIdx.x;
    const int lane = t & 63, wv = t >> 6;
    const int lm = lane & 15, quad = lane >> 4;
    const int nbase = blockIdx.y * 128 + wv * 32;
    const int rowblk = blockIdx.x * 128;

    short8 Bh[2][4], Bl[2][4];
    float bias[2];
    #pragma unroll
    for (int nt = 0; nt < 2; ++nt) {
        const int n = nbase + nt * 16 + lm;
        bias[nt] = bih[n] + bhh[n];
        #pragma unroll
        for (int kk = 0; kk < 4; ++kk) {
            const float4* wp = (const float4*)(Wih + n * E_ + kk * 32 + quad * 8);
            cvt8(wp[0], wp[1], Bh[nt][kk], Bl[nt][kk]);
        }
    }

    for (int slab = 0; slab < 8; ++slab) {
        const int row0 = rowblk + slab * 16;
        const int b = row0 >> tcLog;
        const int tb = row0 & (Tc - 1);
        int len = lengths[b]; len = len < 1 ? 1 : (len > S_ ? S_ : len);
        if (cs + tb >= len) continue;

        const float* xr = x + ((size_t)b * S_ + cs + tb + lm) * E_;
        short8 Ah[4], Al[4];
        #pragma unroll
        for (int kk = 0; kk < 4; ++kk) {
            const float4* ap = (const float4*)(xr + kk * 32 + quad * 8);
            cvt8(ap[0], ap[1], Ah[kk], Al[kk]);
        }
        f4 acc[2] = {{0,0,0,0},{0,0,0,0}};
        #pragma unroll
        for (int kk = 0; kk < 4; ++kk) {
            #pragma unroll
            for (int nt = 0; nt < 2; ++nt) {
                acc[nt] = __builtin_amdgcn_mfma_f32_16x16x32_bf16(Ah[kk], Bh[nt][kk], acc[nt], 0, 0, 0);
                acc[nt] = __builtin_amdgcn_mfma_f32_16x16x32_bf16(Al[kk], Bh[nt][kk], acc[nt], 0, 0, 0);
                acc[nt] = __builtin_amdgcn_mfma_f32_16x16x32_bf16(Ah[kk], Bl[nt][kk], acc[nt], 0, 0, 0);
            }
        }
        float* gp = gx + ((size_t)b * Tc + tb) * G_;
        #pragma unroll
        for (int nt = 0; nt < 2; ++nt) {
            #pragma unroll
            for (int r = 0; r < 4; ++r) {
                gp[(quad * 4 + r) * G_ + nbase + nt * 16 + lm] = acc[nt][r] + bias[nt];
            }
        }
    }
}

// ---------------- K2: MFMA recurrence, grid(B), block(320) -------------------
// waves 0..3: gates (wave w owns cols j = w*16+lm for all 4 gates), wave 4: head.
__global__ __launch_bounds__(320, 1) void k2_recur(
    const float* __restrict__ gx, const int* __restrict__ lengths,
    const float* __restrict__ Whh, const float* __restrict__ hWih,
    const float* __restrict__ hWhh, const float* __restrict__ hbih,
    const float* __restrict__ hbhh, float* __restrict__ out,
    float* __restrict__ stH, float* __restrict__ stC, float* __restrict__ stHK,
    int cs, int Tc)
{
    const int b = blockIdx.x, t = threadIdx.x;
    int len = lengths[b]; len = len < 1 ? 1 : (len > S_ ? S_ : len);
    if (cs > len) return;
    const int ce = cs + Tc;
    const int wave = t >> 6, lane = t & 63, lm = lane & 15, quad = lane >> 4;
    const bool isGate = wave < 4;
    const int w = wave;

    // h as bf16 hi/lo, double-buffered: [parity][hi=0/lo=1][k]
    __shared__ __align__(16) unsigned short hbuf[2][2][H_];

    // ---- loop-invariant weight fragments ----
    short8 Bh[4][2], Bl[4][2];     // gate waves: [gate][kchunk]
    short8 KBh[2][2], KBl[2][2];   // head wave: [tile][kchunk]
    float hbA = 0.f, w0A = 0.f, w1A = 0.f, hbB = 0.f, w0B = 0.f, w1B = 0.f;
    if (isGate) {
        #pragma unroll
        for (int g = 0; g < 4; ++g) {
            const int n = g * 64 + w * 16 + lm;
            #pragma unroll
            for (int kc = 0; kc < 2; ++kc) {
                const float4* wp = (const float4*)(Whh + (size_t)n * H_ + kc * 32 + quad * 8);
                cvt8(wp[0], wp[1], Bh[g][kc], Bl[g][kc]);
            }
        }
    } else {
        #pragma unroll
        for (int kc = 0; kc < 2; ++kc) {
            const float4* kp = (const float4*)(hWih + (size_t)lm * H_ + kc * 32 + quad * 8);
            cvt8(kp[0], kp[1], KBh[0][kc], KBl[0][kc]);
        }
        if (lm < 10) {
            #pragma unroll
            for (int kc = 0; kc < 2; ++kc) {
                const float4* kp = (const float4*)(hWih + (size_t)(16 + lm) * H_ + kc * 32 + quad * 8);
                cvt8(kp[0], kp[1], KBh[1][kc], KBl[1][kc]);
            }
            hbB = hbih[16 + lm] + hbhh[16 + lm];
            w0B = hWhh[(16 + lm) * 2 + 0];
            w1B = hWhh[(16 + lm) * 2 + 1];
        } else {
            #pragma unroll
            for (int kc = 0; kc < 2; ++kc) {
                KBh[1][kc] = (short8)(short)0;
                KBl[1][kc] = (short8)(short)0;
            }
        }
        hbA = hbih[lm] + hbhh[lm];
        w0A = hWhh[lm * 2 + 0];
        w1A = hWhh[lm * 2 + 1];
    }

    // ---- state init / restore ----
    float c = 0.f, h = 0.f, hkA = 0.f, hkB = 0.f;
    if (cs == 0) {
        if (t < 128) ((unsigned short*)hbuf)[t] = 0;   // zero hbuf[0][*][*]
    } else {
        if (t < 64) {
            const float hv = stH[b * 64 + t];
            const short hs = f2bf(hv);
            hbuf[cs & 1][0][t] = (unsigned short)hs;
            hbuf[cs & 1][1][t] = (unsigned short)f2bf(hv - bf2f(hs));
        }
        if (isGate) {
            c = stC[b * 64 + w * 16 + lm];
        } else {
            hkA = stHK[b * 32 + lm];
            if (lm < 10) hkB = stHK[b * 32 + 16 + lm];
        }
    }
    __syncthreads();

    // ---- gx prefetch (distance 2); lane reads cols g*64 + w*16 + lm ----
    const float* gxp = gx + (size_t)b * Tc * G_ + w * 16 + lm;
    float ga0 = 0.f, ga1 = 0.f, ga2 = 0.f, ga3 = 0.f;
    float gb0 = 0.f, gb1 = 0.f, gb2 = 0.f, gb3 = 0.f;
    if (isGate) {
        if (cs < len) { ga0 = gxp[0]; ga1 = gxp[64]; ga2 = gxp[128]; ga3 = gxp[192]; }
        if (cs + 1 < len && cs + 1 < ce) {
            const float* r = gxp + G_;
            gb0 = r[0]; gb1 = r[64]; gb2 = r[128]; gb3 = r[192];
        }
    }

    for (int u = cs; u < ce; ++u) {
        // A-fragments: quad-broadcast reads of h_{u-1} (hi/lo), k = kc*32+quad*8+r.
        const unsigned short* hr = &hbuf[u & 1][0][0];
        const unsigned short* hl = &hbuf[u & 1][1][0];
        const short8 Ah0 = *(const short8*)(hr + quad * 8);
        const short8 Ah1 = *(const short8*)(hr + 32 + quad * 8);
        const short8 Al0 = *(const short8*)(hl + quad * 8);
        const short8 Al1 = *(const short8*)(hl + 32 + quad * 8);

        float vi = 0.f, vf = 0.f, vg = 0.f, vo = 0.f;
        if (isGate) {
            // 3 independent accumulators per gate: chain depth 6 -> 2.
            f4 aA[4], aB[4], aC[4];
            #pragma unroll
            for (int g = 0; g < 4; ++g) { aA[g] = (f4){0,0,0,0}; aB[g] = (f4){0,0,0,0}; aC[g] = (f4){0,0,0,0}; }
            #pragma unroll
            for (int g = 0; g < 4; ++g) aA[g] = __builtin_amdgcn_mfma_f32_16x16x32_bf16(Ah0, Bh[g][0], aA[g], 0, 0, 0);
            #pragma unroll
            for (int g = 0; g < 4; ++g) aB[g] = __builtin_amdgcn_mfma_f32_16x16x32_bf16(Al0, Bh[g][0], aB[g], 0, 0, 0);
            #pragma unroll
            for (int g = 0; g < 4; ++g) aC[g] = __builtin_amdgcn_mfma_f32_16x16x32_bf16(Ah0, Bl[g][0], aC[g], 0, 0, 0);
            #pragma unroll
            for (int g = 0; g < 4; ++g) aA[g] = __builtin_amdgcn_mfma_f32_16x16x32_bf16(Ah1, Bh[g][1], aA[g], 0, 0, 0);
            #pragma unroll
            for (int g = 0; g < 4; ++g) aB[g] = __builtin_amdgcn_mfma_f32_16x16x32_bf16(Al1, Bh[g][1], aB[g], 0, 0, 0);
            #pragma unroll
            for (int g = 0; g < 4; ++g) aC[g] = __builtin_amdgcn_mfma_f32_16x16x32_bf16(Ah1, Bl[g][1], aC[g], 0, 0, 0);
            // all D rows identical (A replicated): element 0 is this lane's col.
            vi = (aA[0][0] + aB[0][0]) + (aC[0][0] + ga0);
            vf = (aA[1][0] + aB[1][0]) + (aC[1][0] + ga1);
            vg = (aA[2][0] + aB[2][0]) + (aC[2][0] + ga2);
            vo = (aA[3][0] + aB[3][0]) + (aC[3][0] + ga3);
        } else if (u >= 1) {
            // head: hk_{u-1} = tanh(hWih·h_{u-1} + hb + hWhh·hk_{u-2})
            f4 zA[2], zB[2], zC[2];
            #pragma unroll
            for (int i = 0; i < 2; ++i) { zA[i] = (f4){0,0,0,0}; zB[i] = (f4){0,0,0,0}; zC[i] = (f4){0,0,0,0}; }
            #pragma unroll
            for (int i = 0; i < 2; ++i) zA[i] = __builtin_amdgcn_mfma_f32_16x16x32_bf16(Ah0, KBh[i][0], zA[i], 0, 0, 0);
            #pragma unroll
            for (int i = 0; i < 2; ++i) zB[i] = __builtin_amdgcn_mfma_f32_16x16x32_bf16(Al0, KBh[i][0], zB[i], 0, 0, 0);
            #pragma unroll
            for (int i = 0; i < 2; ++i) zC[i] = __builtin_amdgcn_mfma_f32_16x16x32_bf16(Ah0, KBl[i][0], zC[i], 0, 0, 0);
            #pragma unroll
            for (int i = 0; i < 2; ++i) zA[i] = __builtin_amdgcn_mfma_f32_16x16x32_bf16(Ah1, KBh[i][1], zA[i], 0, 0, 0);
            #pragma unroll
            for (int i = 0; i < 2; ++i) zB[i] = __builtin_amdgcn_mfma_f32_16x16x32_bf16(Al1, KBh[i][1], zB[i], 0, 0, 0);
            #pragma unroll
            for (int i = 0; i < 2; ++i) zC[i] = __builtin_amdgcn_mfma_f32_16x16x32_bf16(Ah1, KBl[i][1], zC[i], 0, 0, 0);
            const float zAv = (zA[0][0] + zB[0][0]) + (zC[0][0] + hbA);
            const float zBv = (zA[1][0] + zB[1][0]) + (zC[1][0] + hbB);
            const float pA = __shfl_xor(hkA, 1);
            const float pB = __shfl_xor(hkB, 1);
            const float a0_ = (lm & 1) ? pA : hkA, a1_ = (lm & 1) ? hkA : pA;
            const float b0_ = (lm & 1) ? pB : hkB, b1_ = (lm & 1) ? hkB : pB;
            hkA = tanh_fast(zAv + w0A * a0_ + w1A * a1_);
            hkB = tanh_fast(zBv + w0B * b0_ + w1B * b1_);
        }

        if (u == len) {   // uniform per block (1 batch): all waves exit together
            if (!isGate && quad == 0) {
                out[((lm >> 1) * B_ + b) * H2_ + (lm & 1)] = sigm(hkA);
                if (lm < 10) {
                    const int r2 = 16 + lm;
                    out[((r2 >> 1) * B_ + b) * H2_ + (r2 & 1)] = sigm(hkB);
                }
            }
            return;
        }

        if (isGate) {
            c = sigm(vf) * c + sigm(vi) * tanh_fast(vg);
            h = sigm(vo) * tanh_fast(c);
            if (quad == 0) {
                const uint32_t hh = cvtpk(h, 0.f);          // low16 = bf16(h)
                union { uint32_t u; float f; } hf; hf.u = hh << 16;
                const uint32_t ll = cvtpk(h - hf.f, 0.f);   // low16 = bf16(lo)
                hbuf[(u + 1) & 1][0][w * 16 + lm] = (unsigned short)(hh & 0xffffu);
                hbuf[(u + 1) & 1][1][w * 16 + lm] = (unsigned short)(ll & 0xffffu);
            }
            ga0 = gb0; ga1 = gb1; ga2 = gb2; ga3 = gb3;
            const int un = u + 2;
            if (un < len && un < ce) {
                const float* r = gxp + (size_t)(un - cs) * G_;
                gb0 = r[0]; gb1 = r[64]; gb2 = r[128]; gb3 = r[192];
            } else {
                gb0 = gb1 = gb2 = gb3 = 0.f;
            }
        }
        sync_lds_only();
    }

    // chunk complete (len >= ce): persist state (exact fp32 from registers)
    if (isGate) {
        if (quad == 0) {
            stH[b * 64 + w * 16 + lm] = h;
            stC[b * 64 + w * 16 + lm] = c;
        }
    } else if (quad == 0) {
        stHK[b * 32 + lm] = hkA;
        if (lm < 10) stHK[b * 32 + 16 + lm] = hkB;
    }

    if (ce == S_ && len == S_ && !isGate) {
        // lagged final head for h_{S-1} (in hbuf[S_&1], written at u=S_-1)
        const unsigned short* hr = &hbuf[S_ & 1][0][0];
        const unsigned short* hl = &hbuf[S_ & 1][1][0];
        const short8 Ah0 = *(const short8*)(hr + quad * 8);
        const short8 Ah1 = *(const short8*)(hr + 32 + quad * 8);
        const short8 Al0 = *(const short8*)(hl + quad * 8);
        const short8 Al1 = *(const short8*)(hl + 32 + quad * 8);
        f4 z0 = {0,0,0,0}, z1 = {0,0,0,0};
        z0 = __builtin_amdgcn_mfma_f32_16x16x32_bf16(Ah0, KBh[0][0], z0, 0, 0, 0);
        z1 = __builtin_amdgcn_mfma_f32_16x16x32_bf16(Ah0, KBh[1][0], z1, 0, 0, 0);
        z0 = __builtin_amdgcn_mfma_f32_16x16x32_bf16(Al0, KBh[0][0], z0, 0, 0, 0);
        z1 = __builtin_amdgcn_mfma_f32_16x16x32_bf16(Al0, KBh[1][0], z1, 0, 0, 0);
        z0 = __builtin_amdgcn_mfma_f32_16x16x32_bf16(Ah0, KBl[0][0], z0, 0, 0, 0);
        z1 = __builtin_amdgcn_mfma_f32_16x16x32_bf16(Ah0, KBl[1][0], z1, 0, 0, 0);
        z0 = __builtin_amdgcn_mfma_f32_16x16x32_bf16(Ah1, KBh[0][1], z0, 0, 0, 0);
        z1 = __builtin_amdgcn_mfma_f32_16x16x32_bf16(Ah1, KBh[1][1], z1, 0, 0, 0);
        z0 = __builtin_amdgcn_mfma_f32_16x16x32_bf16(Al1, KBh[0][1], z0, 0, 0, 0);
        z1 = __builtin_amdgcn_mfma_f32_16x16x32_bf16(Al1, KBh[1][1], z1, 0, 0, 0);
        z0 = __builtin_amdgcn_mfma_f32_16x16x32_bf16(Ah1, KBl[0][1], z0, 0, 0, 0);
        z1 = __builtin_amdgcn_mfma_f32_16x16x32_bf16(Ah1, KBl[1][1], z1, 0, 0, 0);
        const float zA = z0[0] + hbA;
        const float zB = z1[0] + hbB;
        const float pA = __shfl_xor(hkA, 1);
        const float pB = __shfl_xor(hkB, 1);
        const float a0_ = (lm & 1) ? pA : hkA, a1_ = (lm & 1) ? hkA : pA;
        const float b0_ = (lm & 1) ? pB : hkB, b1_ = (lm & 1) ? hkB : pB;
        const float fA = tanh_fast(zA + w0A * a0_ + w1A * a1_);
        const float fB = tanh_fast(zB + w0B * b0_ + w1B * b1_);
        if (quad == 0) {
            out[((lm >> 1) * B_ + b) * H2_ + (lm & 1)] = sigm(fA);
            if (lm < 10) {
                const int r2 = 16 + lm;
                out[((r2 >> 1) * B_ + b) * H2_ + (r2 & 1)] = sigm(fB);
            }
        }
    }
}

}  // namespace

extern "C" void kernel_launch(void* const* d_in, const int* in_sizes, int n_in,
                              void* d_out, int out_size, void* d_ws, size_t ws_size,
                              hipStream_t stream) {
    const float* x    = (const float*)d_in[0];
    const int*   len  = (const int*)d_in[1];
    const float* Wih  = (const float*)d_in[2];
    const float* Whh  = (const float*)d_in[3];
    const float* bih  = (const float*)d_in[4];
    const float* bhh  = (const float*)d_in[5];
    const float* hWih = (const float*)d_in[6];
    const float* hWhh = (const float*)d_in[7];
    const float* hbih = (const float*)d_in[8];
    const float* hbhh = (const float*)d_in[9];
    float* out = (float*)d_out;

    // pick chunk length fitting the workspace (gx chunk + 160KB state)
    int tcLog = 8;  // Tc = 256
    while (tcLog > 5) {
        size_t need = (size_t)B_ * ((size_t)1 << tcLog) * G_ * 4 + 160 * 1024;
        if (need <= ws_size) break;
        --tcLog;
    }
    const int Tc = 1 << tcLog;
    float* gxbuf = (float*)d_ws;
    size_t gxBytes = (size_t)B_ * Tc * G_ * 4;
    float* stH  = (float*)((char*)d_ws + gxBytes);
    float* stC  = stH + B_ * 64;
    float* stHK = stC + B_ * 64;   // B*32 floats used

    for (int cs = 0; cs < S_; cs += Tc) {
        dim3 g1(B_ * Tc / 128, 2);
        hipLaunchKernelGGL(k1_gemm, g1, dim3(256), 0, stream,
                           x, len, Wih, bih, bhh, gxbuf, cs, tcLog);
        hipLaunchKernelGGL(k2_recur, dim3(B_), dim3(320), 0, stream,
                           gxbuf, len, Whh, hWih, hWhh, hbih, hbhh, out,
                           stH, stC, stHK, cs, Tc);
    }
}